// Round 3
// baseline (733.457 us; speedup 1.0000x reference)
//
#include <hip/hip_runtime.h>

// GrangerNet: 26 tiny MLPs (39 -> 32 -> 1), B = 131072, all fp32.
// Lane = batch row within a 64-row tile; wave w handles effects f = 8k + w.
// W1/b1/W2/b2 accessed wave-uniformly -> SGPR operands for v_fma_f32.
// x_eff tile staged flat into LDS (contiguous in global -> coalesced float4 copy).

#define LAG      20
#define NEFF     26
#define HID      32
#define INDIM    39                  // 19 (eff) + 20 (exp)
#define TB       64                  // batch rows per block
#define NTHREADS 512                 // 8 waves -> 2 waves/SIMD
#define NBATCH   131072
#define XROW     494                 // 19*26 floats per batch row of x_eff

#define TILE_F4      (TB * XROW / 4)         // 7904 float4 = 126,464 B
#define LDS_BYTES    (TB * XROW * 4)         // 126,464 B (<= 160 KiB/CU, > 64 KiB -> attr)

extern "C" __global__ void __launch_bounds__(NTHREADS, 1)
granger_kernel(const float* __restrict__ x_exp,
               const float* __restrict__ x_eff,
               const float* __restrict__ W1,
               const float* __restrict__ b1,
               const float* __restrict__ W2,
               const float* __restrict__ b2,
               float* __restrict__ out)
{
    extern __shared__ float lds[];
    const int tid  = threadIdx.x;
    const int lane = tid & 63;
    const int b0   = blockIdx.x * TB;

    // ---- stage x_eff tile into LDS: flat contiguous copy, coalesced float4 ----
    {
        const float4* __restrict__ src =
            reinterpret_cast<const float4*>(x_eff + (size_t)b0 * XROW);
        float4* __restrict__ dst = reinterpret_cast<float4*>(lds);
#pragma unroll
        for (int j = 0; j < 16; ++j) {                 // 16*512 = 8192 slots
            int slot = tid + j * NTHREADS;             // 0..8191
            if (slot < TILE_F4) dst[slot] = src[slot]; // tail predicated
        }
    }

    // ---- per-lane x_exp row into registers (reused across this wave's effects) ----
    float xe[LAG];
    {
        const float4* __restrict__ xs =
            reinterpret_cast<const float4*>(x_exp + (size_t)(b0 + lane) * LAG);
#pragma unroll
        for (int j = 0; j < LAG / 4; ++j) {
            float4 v = xs[j];
            xe[4*j+0] = v.x; xe[4*j+1] = v.y; xe[4*j+2] = v.z; xe[4*j+3] = v.w;
        }
    }
    __syncthreads();

    // wave id forced into an SGPR so all weight addressing is provably uniform
    const int uw = __builtin_amdgcn_readfirstlane(tid >> 6);   // 0..7
    const float* __restrict__ xrow = lds + lane * XROW;

#pragma unroll 1
    for (int k = 0; k < 4; ++k) {
        const int f = 8 * k + uw;          // waves 0,1: 4 effects; waves 2..7: 3
        if (f >= NEFF) break;              // wave-uniform branch

        const float* __restrict__ w1f = W1 + f * (INDIM * HID);
        const float* __restrict__ b1f = b1 + f * HID;

        float acc[HID];
#pragma unroll
        for (int h = 0; h < HID; ++h) acc[h] = b1f[h];

        // x_cat[0..18] = x_eff[b][i][f]  (LDS, per-lane base + imm offsets)
#pragma unroll
        for (int i = 0; i < LAG - 1; ++i) {
            const float x = xrow[i * NEFF + f];
            const float* __restrict__ wr = w1f + i * HID;
#pragma unroll
            for (int h = 0; h < HID; ++h) acc[h] = fmaf(x, wr[h], acc[h]);
        }
        // x_cat[19..38] = x_exp[b][0..19]  (registers)
#pragma unroll
        for (int j = 0; j < LAG; ++j) {
            const float x = xe[j];
            const float* __restrict__ wr = w1f + (LAG - 1 + j) * HID;
#pragma unroll
            for (int h = 0; h < HID; ++h) acc[h] = fmaf(x, wr[h], acc[h]);
        }

        // layer 2: relu + dot over hidden
        float pred = b2[f];
        const float* __restrict__ w2f = W2 + f * HID;
#pragma unroll
        for (int h = 0; h < HID; ++h)
            pred = fmaf(fmaxf(acc[h], 0.0f), w2f[h], pred);

        // direct scalar store; L2 merges the per-row scatter (write = 5% of traffic)
        out[(size_t)(b0 + lane) * NEFF + f] = pred;
    }
}

extern "C" void kernel_launch(void* const* d_in, const int* in_sizes, int n_in,
                              void* d_out, int out_size, void* d_ws, size_t ws_size,
                              hipStream_t stream)
{
    const float* x_exp = (const float*)d_in[0];
    const float* x_eff = (const float*)d_in[1];
    const float* W1    = (const float*)d_in[2];
    const float* b1    = (const float*)d_in[3];
    const float* W2    = (const float*)d_in[4];
    const float* b2    = (const float*)d_in[5];
    float* out = (float*)d_out;

    // opt in to >64 KiB dynamic LDS (host-side, graph-capture safe, idempotent)
    hipFuncSetAttribute(reinterpret_cast<const void*>(granger_kernel),
                        hipFuncAttributeMaxDynamicSharedMemorySize, LDS_BYTES);

    const int grid = NBATCH / TB;   // 2048 blocks, no tail
    granger_kernel<<<grid, NTHREADS, LDS_BYTES, stream>>>(
        x_exp, x_eff, W1, b1, W2, b2, out);
}